// Round 6
// baseline (446.021 us; speedup 1.0000x reference)
//
#include <hip/hip_runtime.h>
#include <math.h>

#define NN 16384
#define IN_DIM 4
#define HID 64
#define OUT_DIM 2
#define BK 1024             // K floats per tile: 4 KB contiguous per row-visit
#define NT (NN / BK)        // 16 tiles

typedef __bf16 bf16x8 __attribute__((ext_vector_type(8)));
typedef float  f32x4  __attribute__((ext_vector_type(4)));

__device__ __forceinline__ void gload_lds16(const float* g, void* lds) {
    __builtin_amdgcn_global_load_lds(
        (const __attribute__((address_space(1))) void*)g,
        (__attribute__((address_space(3))) void*)lds, 16, 0, 0);
}

// ---------------------------------------------------------------------------
// Kernel 1: messages = tanh(x@W1+b1)@W2+b2, stored TRANSPOSED as bf16:
// msgT[h][node]. 64 nodes per block, 256 blocks.
// ---------------------------------------------------------------------------
__global__ __launch_bounds__(256) void k_messages(
    const float* __restrict__ x, const float* __restrict__ W1,
    const float* __restrict__ b1, const float* __restrict__ W2,
    const float* __restrict__ b2, __bf16* __restrict__ msgT)
{
    __shared__ float  xs[64 * 4];
    __shared__ float  h1[64 * 64];
    __shared__ __bf16 mt[64 * 66];

    const int t = threadIdx.x;
    const int node0 = blockIdx.x * 64;
    xs[t] = x[node0 * 4 + t];
    __syncthreads();

    const int h = t & 63, g = t >> 6;
    for (int n = g * 16; n < g * 16 + 16; ++n) {
        float acc = b1[h];
        #pragma unroll
        for (int k = 0; k < 4; ++k) acc += xs[n * 4 + k] * W1[k * 64 + h];
        h1[n * 64 + h] = tanhf(acc);
    }
    __syncthreads();
    for (int n = g * 16; n < g * 16 + 16; ++n) {
        float acc = b2[h];
        #pragma unroll 8
        for (int k = 0; k < 64; ++k) acc += h1[n * 64 + k] * W2[k * 64 + h];
        mt[h * 66 + n] = (__bf16)acc;
    }
    __syncthreads();
    for (int slot = t; slot < 512; slot += 256) {
        const int r = slot >> 3, c = (slot & 7) * 8;
        bf16x8 v;
        #pragma unroll
        for (int j = 0; j < 8; ++j) v[j] = mt[r * 66 + c + j];
        *(bf16x8*)(msgT + (size_t)r * NN + node0 + c) = v;
    }
}

// ---------------------------------------------------------------------------
// Kernel 2: agg = adj @ messages via bf16 MFMA, LONG-ROW-VISIT version.
// 1024 blocks x 256 thr (4 waves). Block owns 16 rows x full K.
// Per tile (BK=1024): block stages 16 rows x 4 KB CONTIGUOUS per row
// (wave w stages rows 4w..4w+3, 4 back-to-back 1KB gloads per row) into a
// SHARED 64 KB tile, double-buffered (128 KB LDS). Each wave computes a
// different 16-col output group (1 MFMA per kk-step). 2-phase barrier loop:
// STAGE(next) -> compute(cur) -> vmcnt(0)+barrier. Phase rotation mod 16.
// LDS swizzle: 16B chunk c of row r stored at phys chunk c^(r&15), applied
// on BOTH the pre-swizzled global source and the ds_read (rule 21).
// ---------------------------------------------------------------------------
__global__ __launch_bounds__(256, 1) void k_agg(
    const float* __restrict__ adj, const __bf16* __restrict__ msgT,
    float* __restrict__ agg)
{
    __shared__ float As[2][16 * BK];   // 2 x 64 KB = 128 KB

    const int t = threadIdx.x;
    const int wave = t >> 6, lane = t & 63;
    const int m0 = blockIdx.x * 16;
    const int r15 = lane & 15;
    const int kg  = lane >> 4;
    const int phase = blockIdx.x & (NT - 1);

    // B: wave's column group = [16*wave, 16*wave+16)
    const __bf16* bq = msgT + (size_t)(16 * wave + r15) * NN + kg * 8;

    f32x4 acc = {};

#define STAGE(BUF, KT)                                                         \
    {                                                                          \
        _Pragma("unroll")                                                      \
        for (int j = 0; j < 4; ++j) {                                          \
            const int r = 4 * wave + j;                                        \
            const float* src = adj + (size_t)(m0 + r) * NN                     \
                               + (size_t)(KT) * BK + ((lane ^ r) << 2);        \
            float* dst = &As[BUF][r * BK];                                     \
            _Pragma("unroll")                                                  \
            for (int q = 0; q < 4; ++q)                                        \
                gload_lds16(src + q * 256, dst + q * 256);                     \
        }                                                                      \
    }

    // prologue: stage tile 'phase'
    STAGE(0, phase);
    asm volatile("s_waitcnt vmcnt(0)" ::: "memory");
    __syncthreads();

    bf16x8 bc = *(const bf16x8*)(bq + (size_t)phase * BK);
    bf16x8 bn;

    int cur = 0;
    for (int tt = 0; tt < NT; ++tt) {
        const int kt = (phase + tt) & (NT - 1);
        if (tt + 1 < NT) STAGE(cur ^ 1, (phase + tt + 1) & (NT - 1));

        const float* Ab = &As[cur][r15 * BK];
        #pragma unroll
        for (int kk = 0; kk < BK / 32; ++kk) {       // 32 kk-steps
            {   // prefetch next B one step ahead (wraps harmlessly at the end)
                const int nkk = (kk + 1) & 31;
                const int nkt = (kk == 31) ? ((kt + 1) & (NT - 1)) : kt;
                bn = *(const bf16x8*)(bq + (size_t)nkt * BK + nkk * 32);
            }
            f32x4 alo = *(const f32x4*)(Ab + (((kk * 8 + kg * 2 + 0) ^ r15) << 2));
            f32x4 ahi = *(const f32x4*)(Ab + (((kk * 8 + kg * 2 + 1) ^ r15) << 2));
            bf16x8 af;
            af[0] = (__bf16)alo[0]; af[1] = (__bf16)alo[1];
            af[2] = (__bf16)alo[2]; af[3] = (__bf16)alo[3];
            af[4] = (__bf16)ahi[0]; af[5] = (__bf16)ahi[1];
            af[6] = (__bf16)ahi[2]; af[7] = (__bf16)ahi[3];
            acc = __builtin_amdgcn_mfma_f32_16x16x32_bf16(af, bc, acc, 0, 0, 0);
            bc = bn;
        }
        asm volatile("s_waitcnt vmcnt(0)" ::: "memory");
        __syncthreads();
        cur ^= 1;
    }
#undef STAGE

    // epilogue: D lane l: col=l&15, row=4*(l>>4)+j
    #pragma unroll
    for (int j = 0; j < 4; ++j) {
        agg[(size_t)(m0 + kg * 4 + j) * HID + 16 * wave + r15] = acc[j];
    }
}

// ---------------------------------------------------------------------------
// Kernel 3: combined=[x,agg]; out = tanh(tanh(combined@U1+c1)@U2+c2)@Wo + bo.
// 64 nodes/block, 256 blocks.
// ---------------------------------------------------------------------------
__global__ __launch_bounds__(256) void k_update(
    const float* __restrict__ x, const float* __restrict__ agg,
    const float* __restrict__ U1, const float* __restrict__ c1,
    const float* __restrict__ U2, const float* __restrict__ c2,
    const float* __restrict__ Wo, const float* __restrict__ bo,
    float* __restrict__ out)
{
    __shared__ float comb[64 * 73];
    __shared__ float h1s[64 * 66];

    const int t = threadIdx.x, h = t & 63, g = t >> 6;
    const int node0 = blockIdx.x * 64;

    comb[(t >> 2) * 73 + (t & 3)] = x[node0 * 4 + t];
    for (int n = g * 16; n < g * 16 + 16; ++n) {
        comb[n * 73 + 4 + h] = agg[(size_t)(node0 + n) * HID + h];
    }
    __syncthreads();
    for (int n = g * 16; n < g * 16 + 16; ++n) {
        float acc = c1[h];
        #pragma unroll 4
        for (int k = 0; k < 68; ++k) acc += comb[n * 73 + k] * U1[k * 64 + h];
        h1s[n * 66 + h] = tanhf(acc);
    }
    __syncthreads();
    for (int n = g * 16; n < g * 16 + 16; ++n) {
        float acc = c2[h];
        #pragma unroll 8
        for (int k = 0; k < 64; ++k) acc += h1s[n * 66 + k] * U2[k * 64 + h];
        comb[n * 73 + h] = tanhf(acc);
    }
    __syncthreads();
    if (t < 128) {
        const int n = t >> 1, o = t & 1;
        float acc = bo[o];
        #pragma unroll 8
        for (int k = 0; k < 64; ++k) acc += comb[n * 73 + k] * Wo[k * 2 + o];
        out[(size_t)(node0 + n) * 2 + o] = acc;
    }
}

// ---------------------------------------------------------------------------
extern "C" void kernel_launch(void* const* d_in, const int* in_sizes, int n_in,
                              void* d_out, int out_size, void* d_ws, size_t ws_size,
                              hipStream_t stream)
{
    const float* x   = (const float*)d_in[0];
    const float* adj = (const float*)d_in[1];
    const float* W1  = (const float*)d_in[2];
    const float* b1  = (const float*)d_in[3];
    const float* W2  = (const float*)d_in[4];
    const float* b2  = (const float*)d_in[5];
    const float* U1  = (const float*)d_in[6];
    const float* c1  = (const float*)d_in[7];
    const float* U2  = (const float*)d_in[8];
    const float* c2  = (const float*)d_in[9];
    const float* Wo  = (const float*)d_in[10];
    const float* bo  = (const float*)d_in[11];
    float* out = (float*)d_out;

    // ws layout: [msgT: 64*16384 bf16 = 2 MB][agg: 16384*64 f32 = 4 MB]
    __bf16* msgT = (__bf16*)d_ws;
    float*  agg  = (float*)((char*)d_ws + (size_t)HID * NN * sizeof(__bf16));

    k_messages<<<NN / 64, 256, 0, stream>>>(x, W1, b1, W2, b2, msgT);
    k_agg<<<NN / 16, 256, 0, stream>>>(adj, msgT, agg);
    k_update<<<NN / 64, 256, 0, stream>>>(x, agg, U1, c1, U2, c2, Wo, bo, out);
}

// Round 7
// 339.660 us; speedup vs baseline: 1.3131x; 1.3131x over previous
//
#include <hip/hip_runtime.h>
#include <math.h>

#define NN 16384
#define IN_DIM 4
#define HID 64
#define OUT_DIM 2
#define BK 256              // K floats per tile (1KB per row per stage)
#define NT (NN / BK)        // 64 tiles

typedef __bf16 bf16x8 __attribute__((ext_vector_type(8)));
typedef float  f32x4  __attribute__((ext_vector_type(4)));

// NT (non-temporal) cache policy on the adj stream: gfx94x/gfx950 CPol
// bit1 = NT -> no L2/L3 allocation, don't thrash msgT out of L2.
__device__ __forceinline__ void gload_lds16_nt(const float* g, void* lds) {
    __builtin_amdgcn_global_load_lds(
        (const __attribute__((address_space(1))) void*)g,
        (__attribute__((address_space(3))) void*)lds, 16, 0, 2 /*NT*/);
}

template<int N> __device__ __forceinline__ void waitv() {
    asm volatile("s_waitcnt vmcnt(%0)" :: "n"(N) : "memory");
    __builtin_amdgcn_sched_barrier(0);
}

// ---------------------------------------------------------------------------
// Kernel 1: messages = tanh(x@W1+b1)@W2+b2, stored TRANSPOSED as bf16:
// msgT[h][node]. 64 nodes per block, 256 blocks.
// ---------------------------------------------------------------------------
__global__ __launch_bounds__(256) void k_messages(
    const float* __restrict__ x, const float* __restrict__ W1,
    const float* __restrict__ b1, const float* __restrict__ W2,
    const float* __restrict__ b2, __bf16* __restrict__ msgT)
{
    __shared__ float  xs[64 * 4];
    __shared__ float  h1[64 * 64];
    __shared__ __bf16 mt[64 * 66];

    const int t = threadIdx.x;
    const int node0 = blockIdx.x * 64;
    xs[t] = x[node0 * 4 + t];
    __syncthreads();

    const int h = t & 63, g = t >> 6;
    for (int n = g * 16; n < g * 16 + 16; ++n) {
        float acc = b1[h];
        #pragma unroll
        for (int k = 0; k < 4; ++k) acc += xs[n * 4 + k] * W1[k * 64 + h];
        h1[n * 64 + h] = tanhf(acc);
    }
    __syncthreads();
    for (int n = g * 16; n < g * 16 + 16; ++n) {
        float acc = b2[h];
        #pragma unroll 8
        for (int k = 0; k < 64; ++k) acc += h1[n * 64 + k] * W2[k * 64 + h];
        mt[h * 66 + n] = (__bf16)acc;
    }
    __syncthreads();
    for (int slot = t; slot < 512; slot += 256) {
        const int r = slot >> 3, c = (slot & 7) * 8;
        bf16x8 v;
        #pragma unroll
        for (int j = 0; j < 8; ++j) v[j] = mt[r * 66 + c + j];
        *(bf16x8*)(msgT + (size_t)r * NN + node0 + c) = v;
    }
}

// ---------------------------------------------------------------------------
// Kernel 2: agg = adj @ messages via bf16 MFMA. Round-4 structure (best:
// autonomous waves, 1KB-contiguous gload_lds staging, counted vmcnt,
// XOR-swizzled wave-private LDS dbuf, per-wave K-phase rotation) with ONE
// change: adj staging loads carry the NT cache-policy bit so the 1GB
// stream does not allocate in (and thrash) L2/L3; msgT stays L2-resident.
// ---------------------------------------------------------------------------
__global__ __launch_bounds__(128, 1) void k_agg(
    const float* __restrict__ adj, const __bf16* __restrict__ msgT,
    float* __restrict__ agg)
{
    __shared__ float As[2][2][16 * BK];   // 64 KB: [buf][wave][row*BK + chunk*4]

    const int t = threadIdx.x;
    const int wave = t >> 6, lane = t & 63;
    const int m0 = blockIdx.x * 32 + wave * 16;   // wave's first row
    const int r15 = lane & 15;
    const int kg  = lane >> 4;
    const int phase = (blockIdx.x * 2 + wave) & (NT - 1);   // K-phase rotation

    const float*  arow  = adj  + (size_t)m0 * NN;
    const __bf16* bbase = msgT + (size_t)r15 * NN + kg * 8;

    float* wbuf0 = &As[0][wave][0];
    float* wbuf1 = &As[1][wave][0];

    f32x4 acc0 = {}, acc1 = {}, acc2 = {}, acc3 = {};
    bf16x8 bc0, bc1, bc2, bc3, bn0, bn1, bn2, bn3;

    // ---- prologue: stage tile phys=phase (16 x 1KB row-chunks), B(phase,0)
    #pragma unroll
    for (int g = 0; g < 16; ++g)
        gload_lds16_nt(arow + (size_t)g * NN + (size_t)phase * BK + ((lane ^ g) << 2),
                       wbuf0 + g * BK);
    {
        const __bf16* bp = bbase + (size_t)phase * BK;
        bc0 = *(const bf16x8*)(bp);
        bc1 = *(const bf16x8*)(bp + 16 * (size_t)NN);
        bc2 = *(const bf16x8*)(bp + 32 * (size_t)NN);
        bc3 = *(const bf16x8*)(bp + 48 * (size_t)NN);
    }

#define KSTEP(KT, KK, WAITN, DOSTAGE, DOBN)                                        \
    {                                                                              \
        if (DOBN) {                                                                \
            const int nkt = ((KK) == 7) ? (KT) + 1 : (KT);                         \
            const int nkk = ((KK) + 1) & 7;                                        \
            const int npt = (nkt + phase) & (NT - 1);                              \
            const __bf16* bp = bbase + (size_t)npt * BK + nkk * 32;                \
            bn0 = *(const bf16x8*)(bp);                                            \
            bn1 = *(const bf16x8*)(bp + 16 * (size_t)NN);                          \
            bn2 = *(const bf16x8*)(bp + 32 * (size_t)NN);                          \
            bn3 = *(const bf16x8*)(bp + 48 * (size_t)NN);                          \
        }                                                                          \
        if (WAITN) waitv<(WAITN) ? (WAITN) : 63>();                                \
        const float* Ab = (((KT) & 1) ? wbuf1 : wbuf0) + r15 * BK;                 \
        f32x4 alo = *(const f32x4*)(Ab + ((((KK) * 8 + kg * 2 + 0) ^ r15) << 2));  \
        f32x4 ahi = *(const f32x4*)(Ab + ((((KK) * 8 + kg * 2 + 1) ^ r15) << 2));  \
        bf16x8 af;                                                                 \
        af[0] = (__bf16)alo[0]; af[1] = (__bf16)alo[1];                            \
        af[2] = (__bf16)alo[2]; af[3] = (__bf16)alo[3];                            \
        af[4] = (__bf16)ahi[0]; af[5] = (__bf16)ahi[1];                            \
        af[6] = (__bf16)ahi[2]; af[7] = (__bf16)ahi[3];                            \
        acc0 = __builtin_amdgcn_mfma_f32_16x16x32_bf16(af, bc0, acc0, 0, 0, 0);    \
        acc1 = __builtin_amdgcn_mfma_f32_16x16x32_bf16(af, bc1, acc1, 0, 0, 0);    \
        acc2 = __builtin_amdgcn_mfma_f32_16x16x32_bf16(af, bc2, acc2, 0, 0, 0);    \
        acc3 = __builtin_amdgcn_mfma_f32_16x16x32_bf16(af, bc3, acc3, 0, 0, 0);    \
        if (DOSTAGE) {                                                             \
            float* dst = (((KT) & 1) ? wbuf0 : wbuf1);                             \
            const int spt = ((KT) + 1 + phase) & (NT - 1);                         \
            _Pragma("unroll")                                                      \
            for (int q = 0; q < 4; ++q) {                                          \
                const int g = (KK) * 4 + q;                                        \
                gload_lds16_nt(arow + (size_t)g * NN + (size_t)spt * BK            \
                                    + ((lane ^ g) << 2), dst + g * BK);            \
            }                                                                      \
        }                                                                          \
        bc0 = bn0; bc1 = bn1; bc2 = bn2; bc3 = bn3;                                \
        __builtin_amdgcn_sched_barrier(0);                                         \
    }

    // ---- iter 0 (prologue queue: waitv<8> retires the 16 prologue stages) ----
    KSTEP(0, 0, 8, 1, 1);
    #pragma unroll
    for (int kk = 1; kk < 8; ++kk) KSTEP(0, kk, 0, (kk < 4), 1);

    // ---- steady state ----
    for (int kt = 1; kt < NT - 1; ++kt) {
        KSTEP(kt, 0, 20, 1, 1);
        #pragma unroll
        for (int kk = 1; kk < 8; ++kk) KSTEP(kt, kk, 0, (kk < 4), 1);
    }

    // ---- last tile: no staging, no B-prefetch past the end ----
    KSTEP((NT - 1), 0, 20, 0, 1);
    #pragma unroll
    for (int kk = 1; kk < 8; ++kk) KSTEP((NT - 1), kk, 0, 0, (kk != 7));
#undef KSTEP

    // ---- epilogue: write agg (f32). D lane l: col=l&15, row=4*(l>>4)+j ----
    const int rb = m0 + kg * 4;
    f32x4 accs[4] = {acc0, acc1, acc2, acc3};
    #pragma unroll
    for (int tt = 0; tt < 4; ++tt) {
        #pragma unroll
        for (int j = 0; j < 4; ++j) {
            agg[(size_t)(rb + j) * HID + tt * 16 + r15] = accs[tt][j];
        }
    }
}

// ---------------------------------------------------------------------------
// Kernel 3: combined=[x,agg]; out = tanh(tanh(combined@U1+c1)@U2+c2)@Wo + bo.
// 64 nodes/block, 256 blocks.
// ---------------------------------------------------------------------------
__global__ __launch_bounds__(256) void k_update(
    const float* __restrict__ x, const float* __restrict__ agg,
    const float* __restrict__ U1, const float* __restrict__ c1,
    const float* __restrict__ U2, const float* __restrict__ c2,
    const float* __restrict__ Wo, const float* __restrict__ bo,
    float* __restrict__ out)
{
    __shared__ float comb[64 * 73];
    __shared__ float h1s[64 * 66];

    const int t = threadIdx.x, h = t & 63, g = t >> 6;
    const int node0 = blockIdx.x * 64;

    comb[(t >> 2) * 73 + (t & 3)] = x[node0 * 4 + t];
    for (int n = g * 16; n < g * 16 + 16; ++n) {
        comb[n * 73 + 4 + h] = agg[(size_t)(node0 + n) * HID + h];
    }
    __syncthreads();
    for (int n = g * 16; n < g * 16 + 16; ++n) {
        float acc = c1[h];
        #pragma unroll 4
        for (int k = 0; k < 68; ++k) acc += comb[n * 73 + k] * U1[k * 64 + h];
        h1s[n * 66 + h] = tanhf(acc);
    }
    __syncthreads();
    for (int n = g * 16; n < g * 16 + 16; ++n) {
        float acc = c2[h];
        #pragma unroll 8
        for (int k = 0; k < 64; ++k) acc += h1s[n * 66 + k] * U2[k * 64 + h];
        comb[n * 73 + h] = tanhf(acc);
    }
    __syncthreads();
    if (t < 128) {
        const int n = t >> 1, o = t & 1;
        float acc = bo[o];
        #pragma unroll 8
        for (int k = 0; k < 64; ++k) acc += comb[n * 73 + k] * Wo[k * 2 + o];
        out[(size_t)(node0 + n) * 2 + o] = acc;
    }
}

// ---------------------------------------------------------------------------
extern "C" void kernel_launch(void* const* d_in, const int* in_sizes, int n_in,
                              void* d_out, int out_size, void* d_ws, size_t ws_size,
                              hipStream_t stream)
{
    const float* x   = (const float*)d_in[0];
    const float* adj = (const float*)d_in[1];
    const float* W1  = (const float*)d_in[2];
    const float* b1  = (const float*)d_in[3];
    const float* W2  = (const float*)d_in[4];
    const float* b2  = (const float*)d_in[5];
    const float* U1  = (const float*)d_in[6];
    const float* c1  = (const float*)d_in[7];
    const float* U2  = (const float*)d_in[8];
    const float* c2  = (const float*)d_in[9];
    const float* Wo  = (const float*)d_in[10];
    const float* bo  = (const float*)d_in[11];
    float* out = (float*)d_out;

    // ws layout: [msgT: 64*16384 bf16 = 2 MB][agg: 16384*64 f32 = 4 MB]
    __bf16* msgT = (__bf16*)d_ws;
    float*  agg  = (float*)((char*)d_ws + (size_t)HID * NN * sizeof(__bf16));

    k_messages<<<NN / 64, 256, 0, stream>>>(x, W1, b1, W2, b2, msgT);
    k_agg<<<NN / 32, 128, 0, stream>>>(adj, msgT, agg);
    k_update<<<NN / 64, 256, 0, stream>>>(x, agg, U1, c1, U2, c2, Wo, bo, out);
}